// Round 4
// baseline (2332.342 us; speedup 1.0000x reference)
//
#include <hip/hip_runtime.h>
#include <stdint.h>

// Problem constants (B,N,DIM,HEADS,DEPTH = 2,2048,1024,16,6)
#define B_     2
#define N_TOK  2048
#define DIM_   1024
#define HEADS_ 16
#define DEPTH_ 6
#define HID_   4096
#define DH_    64
#define MROWS_ (B_ * N_TOK)       // 4096 token rows
#define SCALE_ 0.125f             // DH^-0.5

typedef __bf16 bf16x8 __attribute__((ext_vector_type(8)));
typedef float  f32x4  __attribute__((ext_vector_type(4)));
typedef float  f32x16 __attribute__((ext_vector_type(16)));

__device__ __forceinline__ unsigned short f2bf(float f) {
  unsigned int u = __float_as_uint(f);
  u += 0x7FFFu + ((u >> 16) & 1u);
  return (unsigned short)(u >> 16);
}

__device__ __forceinline__ f32x4 mfma16(bf16x8 a, bf16x8 b, f32x4 c) {
  return __builtin_amdgcn_mfma_f32_16x16x32_bf16(a, b, c, 0, 0, 0);
}
__device__ __forceinline__ f32x16 mfma32(bf16x8 a, bf16x8 b, f32x16 c) {
  return __builtin_amdgcn_mfma_f32_32x32x16_bf16(a, b, c, 0, 0, 0);
}
__device__ __forceinline__ f32x16 zero16() {
  f32x16 z;
  #pragma unroll
  for (int e = 0; e < 16; ++e) z[e] = 0.f;
  return z;
}

// async global->LDS, 16B per lane. dst must be wave-uniform; HW adds lane*16.
__device__ __forceinline__ void gload_lds16(const unsigned short* g, unsigned short* l) {
  __builtin_amdgcn_global_load_lds(
      (const __attribute__((address_space(1))) unsigned int*)g,
      (__attribute__((address_space(3))) unsigned int*)l, 16, 0, 0);
}

// ---------------------------------------------------------------------------
// LayerNorm: one block per token row; fp32 in (x), bf16 out (h).
// ---------------------------------------------------------------------------
__global__ __launch_bounds__(256) void ln_kernel(
    const float* __restrict__ x, unsigned short* __restrict__ h,
    const float* __restrict__ gw, const float* __restrict__ bw) {
  int row = blockIdx.x;
  int t = threadIdx.x;
  const float* xr = x + (size_t)row * DIM_;
  float4 v = reinterpret_cast<const float4*>(xr)[t];
  float s = v.x + v.y + v.z + v.w;
  float q = v.x * v.x + v.y * v.y + v.z * v.z + v.w * v.w;
  for (int m = 1; m < 64; m <<= 1) { s += __shfl_xor(s, m); q += __shfl_xor(q, m); }
  __shared__ float rs[4], rq[4];
  int lane = t & 63, w = t >> 6;
  if (lane == 0) { rs[w] = s; rq[w] = q; }
  __syncthreads();
  s = rs[0] + rs[1] + rs[2] + rs[3];
  q = rq[0] + rq[1] + rq[2] + rq[3];
  float mean = s * (1.0f / DIM_);
  float var  = q * (1.0f / DIM_) - mean * mean;
  float rstd = rsqrtf(var + 1e-5f);
  float4 gv = reinterpret_cast<const float4*>(gw)[t];
  float4 bv = reinterpret_cast<const float4*>(bw)[t];
  ushort4 ov;
  ov.x = f2bf((v.x - mean) * rstd * gv.x + bv.x);
  ov.y = f2bf((v.y - mean) * rstd * gv.y + bv.y);
  ov.z = f2bf((v.z - mean) * rstd * gv.z + bv.z);
  ov.w = f2bf((v.w - mean) * rstd * gv.w + bv.w);
  reinterpret_cast<ushort4*>(h + (size_t)row * DIM_)[t] = ov;
}

// ---------------------------------------------------------------------------
// Weight transpose+convert: W fp32 [K][Nn] -> Wt bf16 [Nn][K].
// ---------------------------------------------------------------------------
__global__ __launch_bounds__(256) void transpose_w(
    const float* __restrict__ W, unsigned short* __restrict__ Wt, int K, int Nn) {
  __shared__ unsigned short tile[32][33];
  int n0 = blockIdx.x * 32, k0 = blockIdx.y * 32;
  int tx = threadIdx.x & 31, ty = threadIdx.x >> 5;
  #pragma unroll
  for (int r = ty; r < 32; r += 8)
    tile[r][tx] = f2bf(W[(size_t)(k0 + r) * Nn + n0 + tx]);
  __syncthreads();
  #pragma unroll
  for (int r = ty; r < 32; r += 8)
    Wt[(size_t)(n0 + r) * K + k0 + tx] = tile[tx][r];
}

// ---------------------------------------------------------------------------
// V transpose: qkv bf16 [4096][3072] (v cols 2048..3071) -> vt [32][64][2048]
// ---------------------------------------------------------------------------
__global__ __launch_bounds__(256) void vtrans(
    const unsigned short* __restrict__ qkv, unsigned short* __restrict__ vt) {
  __shared__ unsigned short t[64][65];
  int b = blockIdx.y >> 4, h = blockIdx.y & 15;
  int n0 = blockIdx.x * 64;
  int tx = threadIdx.x & 63, ty = threadIdx.x >> 6;
  const unsigned short* src = qkv + ((size_t)(b * N_TOK + n0)) * (3 * DIM_) + 2 * DIM_ + h * DH_;
  #pragma unroll
  for (int r = ty; r < 64; r += 4) t[r][tx] = src[(size_t)r * (3 * DIM_) + tx];
  __syncthreads();
  unsigned short* dst = vt + ((size_t)blockIdx.y * DH_) * N_TOK + n0;
  #pragma unroll
  for (int r = ty; r < 64; r += 4) dst[(size_t)r * N_TOK + tx] = t[tx][r];
}

// ---------------------------------------------------------------------------
// bf16 MFMA GEMM (m97-structure) with optional split-K via gridDim.z.
// A bf16 [M][K] row-major, Bt bf16 [Nn][K] (B^T), bias fp32 [Nn].
// EP 0: out bf16 = acc+bias ; EP 1: out bf16 = gelu(acc+bias) ;
// EP 2: fp32 atomicAdd into Cf (residual); bias added by z==0 only.
// ---------------------------------------------------------------------------
#define EP_BF16       0
#define EP_BF16_GELU  1
#define EP_F32_RESID  2

template <int EP>
__global__ __launch_bounds__(256) void gemm_kernel(
    const unsigned short* __restrict__ A, const unsigned short* __restrict__ Bt,
    const float* __restrict__ bias, unsigned short* __restrict__ Cb,
    float* __restrict__ Cf, int M, int Nn, int K) {
  int brow = blockIdx.x * 128;
  int bcol = blockIdx.y * 128;
  int Ks = K / gridDim.z;                    // K-chunk this block reduces
  int kbase = blockIdx.z * Ks;
  int lane = threadIdx.x & 63, wave = threadIdx.x >> 6;
  int i = lane & 15, g = lane >> 4;
  int wr = wave >> 1, wc = wave & 1;
  __shared__ unsigned short Al[2][128 * 32];
  __shared__ unsigned short Bl[2][128 * 32];

  f32x4 zero4 = {0.f, 0.f, 0.f, 0.f};
  f32x4 acc[4][4];
  #pragma unroll
  for (int m = 0; m < 4; ++m)
    #pragma unroll
    for (int n = 0; n < 4; ++n) acc[m][n] = zero4;

  auto stage = [&](int buf, int k0) {
    #pragma unroll
    for (int c = 0; c < 2; ++c) {
      int ch = wave * 2 + c;
      int row = ch * 16 + (lane >> 2);
      int k8 = (lane & 3) * 8;
      gload_lds16(A + (size_t)(brow + row) * K + kbase + k0 + k8, &Al[buf][ch * 512]);
      gload_lds16(Bt + (size_t)(bcol + row) * K + kbase + k0 + k8, &Bl[buf][ch * 512]);
    }
  };

  int NT = Ks / 32;
  stage(0, 0);
  for (int t = 0; t < NT; ++t) {
    __syncthreads();
    if (t + 1 < NT) stage((t + 1) & 1, (t + 1) * 32);
    int buf = t & 1;
    bf16x8 af[4], bfr[4];
    #pragma unroll
    for (int m = 0; m < 4; ++m)
      af[m] = *reinterpret_cast<const bf16x8*>(&Al[buf][(wr * 64 + m * 16 + i) * 32 + g * 8]);
    #pragma unroll
    for (int n = 0; n < 4; ++n)
      bfr[n] = *reinterpret_cast<const bf16x8*>(&Bl[buf][(wc * 64 + n * 16 + i) * 32 + g * 8]);
    #pragma unroll
    for (int m = 0; m < 4; ++m)
      #pragma unroll
      for (int n = 0; n < 4; ++n)
        acc[m][n] = mfma16(af[m], bfr[n], acc[m][n]);
  }

  int rowbase = brow + wr * 64;
  int colbase = bcol + wc * 64;
  #pragma unroll
  for (int m = 0; m < 4; ++m) {
    #pragma unroll
    for (int n = 0; n < 4; ++n) {
      int col = colbase + n * 16 + i;
      float bs = bias[col];
      #pragma unroll
      for (int r = 0; r < 4; ++r) {
        int row = rowbase + m * 16 + g * 4 + r;
        float v = acc[m][n][r] + bs;
        if constexpr (EP == EP_BF16) {
          Cb[(size_t)row * Nn + col] = f2bf(v);
        } else if constexpr (EP == EP_BF16_GELU) {
          float gg = 0.5f * v * (1.0f + erff(v * 0.70710678118f));
          Cb[(size_t)row * Nn + col] = f2bf(gg);
        } else {
          size_t idx = (size_t)row * Nn + col;
          float vv = acc[m][n][r] + (blockIdx.z == 0 ? bs : 0.f);
          atomicAdd(&Cf[idx], vv);            // split-K partial + residual
        }
      }
    }
  }
}

// ---------------------------------------------------------------------------
// Flash attention fwd, swapped-QK^T 32x32 MFMA, in-register softmax.
// grid (N_TOK/128, B_*HEADS_), 256 threads = 4 waves x 32 q-rows.
// ---------------------------------------------------------------------------
__global__ __launch_bounds__(256) void attn_kernel(
    const unsigned short* __restrict__ qkv, const unsigned short* __restrict__ vt,
    unsigned short* __restrict__ o) {
  int qt = blockIdx.x, bh = blockIdx.y;
  int b = bh >> 4, h = bh & 15;
  int tid = threadIdx.x, lane = tid & 63, wave = tid >> 6;
  int q5 = lane & 31, hi = lane >> 5;
  __shared__ unsigned short Kl[2][64 * 64];
  __shared__ unsigned short Vl[2][64 * 64];

  const size_t qstr = 3 * DIM_;
  int qrow = qt * 128 + wave * 32 + q5;

  bf16x8 qa[4];
  #pragma unroll
  for (int f = 0; f < 4; ++f)
    qa[f] = *reinterpret_cast<const bf16x8*>(
        qkv + (size_t)(b * N_TOK + qrow) * qstr + h * DH_ + f * 16 + hi * 8);

  f32x16 oacc[2];
  oacc[0] = zero16(); oacc[1] = zero16();
  float m = -1e30f, l = 0.f;

  const unsigned short* kbase = qkv + (size_t)b * N_TOK * qstr + DIM_ + h * DH_;
  const unsigned short* vbase = vt + (size_t)bh * DH_ * N_TOK;
  uint4 kreg[2], vreg[2];

  auto issue = [&](int j0) {
    #pragma unroll
    for (int p = 0; p < 2; ++p) {
      int c = p * 256 + tid;
      int row = c >> 3, off = c & 7;
      kreg[p] = *reinterpret_cast<const uint4*>(kbase + (size_t)(j0 + row) * qstr + off * 8);
      vreg[p] = *reinterpret_cast<const uint4*>(vbase + (size_t)row * N_TOK + j0 + off * 8);
    }
  };
  auto commit = [&](int buf) {
    #pragma unroll
    for (int p = 0; p < 2; ++p) {
      int c = p * 256 + tid;
      int row = c >> 3, off = c & 7;
      int sw = row * 64 + ((off * 8) ^ ((row & 7) << 3));
      *reinterpret_cast<uint4*>(&Kl[buf][sw]) = kreg[p];
      *reinterpret_cast<uint4*>(&Vl[buf][sw]) = vreg[p];
    }
  };

  issue(0); commit(0);
  int cur = 0;
  for (int jt = 0; jt < N_TOK / 64; ++jt) {
    __syncthreads();
    if (jt + 1 < N_TOK / 64) issue((jt + 1) * 64);

    f32x16 sacc0 = zero16(), sacc1 = zero16();
    #pragma unroll
    for (int f = 0; f < 4; ++f) {
      int r0 = q5;
      int r1 = 32 + q5;
      bf16x8 ka0 = *reinterpret_cast<const bf16x8*>(
          &Kl[cur][r0 * 64 + ((f * 16 + hi * 8) ^ ((r0 & 7) << 3))]);
      bf16x8 ka1 = *reinterpret_cast<const bf16x8*>(
          &Kl[cur][r1 * 64 + ((f * 16 + hi * 8) ^ ((r1 & 7) << 3))]);
      sacc0 = mfma32(ka0, qa[f], sacc0);
      sacc1 = mfma32(ka1, qa[f], sacc1);
    }

    float pe0[16], pe1[16];
    float tmax = -1e30f;
    #pragma unroll
    for (int r = 0; r < 16; ++r) {
      pe0[r] = sacc0[r] * SCALE_;
      pe1[r] = sacc1[r] * SCALE_;
      tmax = fmaxf(tmax, fmaxf(pe0[r], pe1[r]));
    }
    tmax = fmaxf(tmax, __shfl_xor(tmax, 32));
    float mn = fmaxf(m, tmax);
    float al = __expf(m - mn);
    m = mn;
    float ps = 0.f;
    #pragma unroll
    for (int r = 0; r < 16; ++r) {
      pe0[r] = __expf(pe0[r] - mn); ps += pe0[r];
      pe1[r] = __expf(pe1[r] - mn); ps += pe1[r];
    }
    ps += __shfl_xor(ps, 32);
    l = l * al + ps;
    oacc[0] *= al;
    oacc[1] *= al;

    unsigned int cc0[8], cc1[8], dd0[8], dd1[8];
    #pragma unroll
    for (int t = 0; t < 8; ++t) {
      union { __bf16 hh[2]; unsigned int u; } p0, p1;
      p0.hh[0] = (__bf16)pe0[2 * t]; p0.hh[1] = (__bf16)pe0[2 * t + 1];
      p1.hh[0] = (__bf16)pe1[2 * t]; p1.hh[1] = (__bf16)pe1[2 * t + 1];
      cc0[t] = p0.u; cc1[t] = p1.u;
      dd0[t] = __shfl_xor(p0.u, 32);
      dd1[t] = __shfl_xor(p1.u, 32);
    }
    bf16x8 pb[4];
    #pragma unroll
    for (int half = 0; half < 2; ++half) {
      int t0 = half * 4;
      union { unsigned int w[4]; bf16x8 v; } u0, u1;
      u0.w[0] = hi ? dd0[t0 + 2] : cc0[t0 + 0];
      u0.w[1] = hi ? dd0[t0 + 3] : cc0[t0 + 1];
      u0.w[2] = hi ? cc0[t0 + 2] : dd0[t0 + 0];
      u0.w[3] = hi ? cc0[t0 + 3] : dd0[t0 + 1];
      u1.w[0] = hi ? dd1[t0 + 2] : cc1[t0 + 0];
      u1.w[1] = hi ? dd1[t0 + 3] : cc1[t0 + 1];
      u1.w[2] = hi ? cc1[t0 + 2] : dd1[t0 + 0];
      u1.w[3] = hi ? cc1[t0 + 3] : dd1[t0 + 1];
      pb[half] = u0.v;
      pb[2 + half] = u1.v;
    }

    #pragma unroll
    for (int dt = 0; dt < 2; ++dt) {
      int row = dt * 32 + q5;
      #pragma unroll
      for (int ks = 0; ks < 4; ++ks) {
        bf16x8 va = *reinterpret_cast<const bf16x8*>(
            &Vl[cur][row * 64 + ((ks * 16 + hi * 8) ^ ((row & 7) << 3))]);
        oacc[dt] = mfma32(va, pb[ks], oacc[dt]);
      }
    }
    if (jt + 1 < N_TOK / 64) commit(cur ^ 1);
    cur ^= 1;
  }

  float inv = 1.0f / l;
  unsigned short* ob = o + (size_t)(b * N_TOK + qrow) * DIM_ + h * DH_;
  #pragma unroll
  for (int dt = 0; dt < 2; ++dt)
    #pragma unroll
    for (int rq = 0; rq < 4; ++rq) {
      ushort4 st;
      st.x = f2bf(oacc[dt][rq * 4 + 0] * inv);
      st.y = f2bf(oacc[dt][rq * 4 + 1] * inv);
      st.z = f2bf(oacc[dt][rq * 4 + 2] * inv);
      st.w = f2bf(oacc[dt][rq * 4 + 3] * inv);
      *reinterpret_cast<ushort4*>(ob + dt * 32 + rq * 8 + hi * 4) = st;
    }
}

// ---------------------------------------------------------------------------
extern "C" void kernel_launch(void* const* d_in, const int* in_sizes, int n_in,
                              void* d_out, int out_size, void* d_ws, size_t ws_size,
                              hipStream_t stream) {
  (void)in_sizes; (void)n_in; (void)out_size; (void)ws_size;
  const float* x_in = (const float*)d_in[0];
  const float* Wqkv = (const float*)d_in[1];
  const float* bqkv = (const float*)d_in[2];
  const float* Wo   = (const float*)d_in[3];
  const float* bo   = (const float*)d_in[4];
  const float* W1   = (const float*)d_in[5];
  const float* bm1  = (const float*)d_in[6];
  const float* W2   = (const float*)d_in[7];
  const float* bm2  = (const float*)d_in[8];
  const float* ln1g = (const float*)d_in[9];
  const float* ln1b = (const float*)d_in[10];
  const float* ln2g = (const float*)d_in[11];
  const float* ln2b = (const float*)d_in[12];
  float* x = (float*)d_out;                  // residual stream, fp32, in-place

  char* ws = (char*)d_ws;
  unsigned short* wt  = (unsigned short*)(ws);                              // 8 MB
  unsigned short* hbf = (unsigned short*)(ws + (size_t)8  * 1024 * 1024);   // 8 MB
  unsigned short* qkv = (unsigned short*)(ws + (size_t)16 * 1024 * 1024);   // 24 MB
  unsigned short* vtb = (unsigned short*)(ws + (size_t)40 * 1024 * 1024);   // 8 MB
  unsigned short* ob  = (unsigned short*)(ws + (size_t)48 * 1024 * 1024);   // 8 MB
  unsigned short* mid = (unsigned short*)(ws + (size_t)56 * 1024 * 1024);   // 32 MB

  hipMemcpyAsync(x, x_in, (size_t)MROWS_ * DIM_ * sizeof(float),
                 hipMemcpyDeviceToDevice, stream);

  for (int l = 0; l < DEPTH_; ++l) {
    const float* wqkv_l = Wqkv + (size_t)l * DIM_ * 3 * DIM_;
    const float* wo_l   = Wo   + (size_t)l * DIM_ * DIM_;
    const float* w1_l   = W1   + (size_t)l * DIM_ * HID_;
    const float* w2_l   = W2   + (size_t)l * HID_ * DIM_;

    // --- PreNorm + Attention ---
    ln_kernel<<<MROWS_, 256, 0, stream>>>(x, hbf, ln1g + l * DIM_, ln1b + l * DIM_);
    transpose_w<<<dim3(3 * DIM_ / 32, DIM_ / 32), 256, 0, stream>>>(wqkv_l, wt, DIM_, 3 * DIM_);
    gemm_kernel<EP_BF16><<<dim3(MROWS_ / 128, 3 * DIM_ / 128, 1), 256, 0, stream>>>(
        hbf, wt, bqkv + (size_t)l * 3 * DIM_, qkv, nullptr, MROWS_, 3 * DIM_, DIM_);
    vtrans<<<dim3(N_TOK / 64, B_ * HEADS_), 256, 0, stream>>>(qkv, vtb);
    attn_kernel<<<dim3(N_TOK / 128, B_ * HEADS_), 256, 0, stream>>>(qkv, vtb, ob);
    transpose_w<<<dim3(DIM_ / 32, DIM_ / 32), 256, 0, stream>>>(wo_l, wt, DIM_, DIM_);
    gemm_kernel<EP_F32_RESID><<<dim3(MROWS_ / 128, DIM_ / 128, 2), 256, 0, stream>>>(
        ob, wt, bo + (size_t)l * DIM_, nullptr, x, MROWS_, DIM_, DIM_);

    // --- PreNorm + MLP ---
    ln_kernel<<<MROWS_, 256, 0, stream>>>(x, hbf, ln2g + l * DIM_, ln2b + l * DIM_);
    transpose_w<<<dim3(HID_ / 32, DIM_ / 32), 256, 0, stream>>>(w1_l, wt, DIM_, HID_);
    gemm_kernel<EP_BF16_GELU><<<dim3(MROWS_ / 128, HID_ / 128, 1), 256, 0, stream>>>(
        hbf, wt, bm1 + (size_t)l * HID_, mid, nullptr, MROWS_, HID_, DIM_);
    transpose_w<<<dim3(DIM_ / 32, HID_ / 32), 256, 0, stream>>>(w2_l, wt, HID_, DIM_);
    gemm_kernel<EP_F32_RESID><<<dim3(MROWS_ / 128, DIM_ / 128, 4), 256, 0, stream>>>(
        mid, wt, bm2 + (size_t)l * DIM_, nullptr, x, MROWS_, DIM_, HID_);
  }
}

// Round 7
// 1967.131 us; speedup vs baseline: 1.1857x; 1.1857x over previous
//
#include <hip/hip_runtime.h>
#include <stdint.h>

// Problem constants (B,N,DIM,HEADS,DEPTH = 2,2048,1024,16,6)
#define B_     2
#define N_TOK  2048
#define DIM_   1024
#define HEADS_ 16
#define DEPTH_ 6
#define HID_   4096
#define DH_    64
#define MROWS_ (B_ * N_TOK)       // 4096 token rows
#define SCALE_ 0.125f             // DH^-0.5
#define PSTR_  ((size_t)MROWS_ * DIM_)   // partial-buffer stride (elements)

typedef __bf16 bf16x8 __attribute__((ext_vector_type(8)));
typedef float  f32x4  __attribute__((ext_vector_type(4)));
typedef float  f32x16 __attribute__((ext_vector_type(16)));

__device__ __forceinline__ unsigned short f2bf(float f) {
  unsigned int u = __float_as_uint(f);
  u += 0x7FFFu + ((u >> 16) & 1u);
  return (unsigned short)(u >> 16);
}
__device__ __forceinline__ float bf2f(unsigned short u) {
  return __uint_as_float((unsigned int)u << 16);
}

__device__ __forceinline__ f32x4 mfma16(bf16x8 a, bf16x8 b, f32x4 c) {
  return __builtin_amdgcn_mfma_f32_16x16x32_bf16(a, b, c, 0, 0, 0);
}
__device__ __forceinline__ f32x16 mfma32(bf16x8 a, bf16x8 b, f32x16 c) {
  return __builtin_amdgcn_mfma_f32_32x32x16_bf16(a, b, c, 0, 0, 0);
}
__device__ __forceinline__ f32x16 zero16() {
  f32x16 z;
  #pragma unroll
  for (int e = 0; e < 16; ++e) z[e] = 0.f;
  return z;
}

// async global->LDS, 16B per lane. dst must be wave-uniform; HW adds lane*16.
__device__ __forceinline__ void gload_lds16(const unsigned short* g, unsigned short* l) {
  __builtin_amdgcn_global_load_lds(
      (const __attribute__((address_space(1))) unsigned int*)g,
      (__attribute__((address_space(3))) unsigned int*)l, 16, 0, 0);
}

// ---------------------------------------------------------------------------
// x copy (replaces hipMemcpyAsync): grid 4096 x 256, one float4/thread.
// ---------------------------------------------------------------------------
__global__ __launch_bounds__(256) void copy_x(const float4* __restrict__ src,
                                              float4* __restrict__ dst) {
  int i = blockIdx.x * 256 + threadIdx.x;
  dst[i] = src[i];
}

// ---------------------------------------------------------------------------
// LayerNorm with fused split-K reduction: if nparts>0, first
//   x[row] += bias2 + sum_z bf2f(parts[z])   (persistent residual update)
// then h = LN(x) in bf16. One block per token row.
// ---------------------------------------------------------------------------
__global__ __launch_bounds__(256) void ln_fused(
    float* __restrict__ x, unsigned short* __restrict__ h,
    const float* __restrict__ gw, const float* __restrict__ bw,
    const unsigned short* __restrict__ parts, int nparts,
    const float* __restrict__ bias2) {
  int row = blockIdx.x;
  int t = threadIdx.x;
  size_t i4 = (size_t)row * 256 + t;      // float4 index
  float4* x4 = reinterpret_cast<float4*>(x);
  float4 v = x4[i4];
  if (nparts > 0) {
    float4 bb = reinterpret_cast<const float4*>(bias2)[t];
    v.x += bb.x; v.y += bb.y; v.z += bb.z; v.w += bb.w;
    const ushort4* p4 = reinterpret_cast<const ushort4*>(parts);
    #pragma unroll 4
    for (int z = 0; z < nparts; ++z) {
      ushort4 p = p4[(size_t)z * (PSTR_ / 4) + i4];
      v.x += bf2f(p.x); v.y += bf2f(p.y); v.z += bf2f(p.z); v.w += bf2f(p.w);
    }
    x4[i4] = v;
  }
  float s = v.x + v.y + v.z + v.w;
  float q = v.x * v.x + v.y * v.y + v.z * v.z + v.w * v.w;
  for (int m = 1; m < 64; m <<= 1) { s += __shfl_xor(s, m); q += __shfl_xor(q, m); }
  __shared__ float rs[4], rq[4];
  int lane = t & 63, w = t >> 6;
  if (lane == 0) { rs[w] = s; rq[w] = q; }
  __syncthreads();
  s = rs[0] + rs[1] + rs[2] + rs[3];
  q = rq[0] + rq[1] + rq[2] + rq[3];
  float mean = s * (1.0f / DIM_);
  float var  = q * (1.0f / DIM_) - mean * mean;
  float rstd = rsqrtf(var + 1e-5f);
  float4 gv = reinterpret_cast<const float4*>(gw)[t];
  float4 bv = reinterpret_cast<const float4*>(bw)[t];
  ushort4 ov;
  ov.x = f2bf((v.x - mean) * rstd * gv.x + bv.x);
  ov.y = f2bf((v.y - mean) * rstd * gv.y + bv.y);
  ov.z = f2bf((v.z - mean) * rstd * gv.z + bv.z);
  ov.w = f2bf((v.w - mean) * rstd * gv.w + bv.w);
  reinterpret_cast<ushort4*>(h + (size_t)row * DIM_)[t] = ov;
}

// ---------------------------------------------------------------------------
// Final residual update after last layer's MLP2: x += bias2 + sum parts.
// ---------------------------------------------------------------------------
__global__ __launch_bounds__(256) void final_add(
    float* __restrict__ x, const unsigned short* __restrict__ parts,
    const float* __restrict__ bias2) {
  size_t i4 = (size_t)blockIdx.x * 256 + threadIdx.x;
  float4* x4 = reinterpret_cast<float4*>(x);
  float4 v = x4[i4];
  float4 bb = reinterpret_cast<const float4*>(bias2)[i4 & 255];
  v.x += bb.x; v.y += bb.y; v.z += bb.z; v.w += bb.w;
  const ushort4* p4 = reinterpret_cast<const ushort4*>(parts);
  #pragma unroll
  for (int z = 0; z < 4; ++z) {
    ushort4 p = p4[(size_t)z * (PSTR_ / 4) + i4];
    v.x += bf2f(p.x); v.y += bf2f(p.y); v.z += bf2f(p.z); v.w += bf2f(p.w);
  }
  x4[i4] = v;
}

// ---------------------------------------------------------------------------
// Weight transpose+convert: W fp32 [K][Nn] -> Wt bf16 [Nn][K].
// grid (Nn/32, K/32), 256 threads (32x8).
// ---------------------------------------------------------------------------
__global__ __launch_bounds__(256) void transpose_w(
    const float* __restrict__ W, unsigned short* __restrict__ Wt, int K, int Nn) {
  __shared__ unsigned short tile[32][33];
  int n0 = blockIdx.x * 32, k0 = blockIdx.y * 32;
  int tx = threadIdx.x & 31, ty = threadIdx.x >> 5;
  #pragma unroll
  for (int r = ty; r < 32; r += 8)
    tile[r][tx] = f2bf(W[(size_t)(k0 + r) * Nn + n0 + tx]);
  __syncthreads();
  #pragma unroll
  for (int r = ty; r < 32; r += 8)
    Wt[(size_t)(n0 + r) * K + k0 + tx] = tile[tx][r];
}

// ---------------------------------------------------------------------------
// V transpose: qkv bf16 [4096][3072] (v cols 2048..3071) -> vt [32][64][2048]
// ---------------------------------------------------------------------------
__global__ __launch_bounds__(256) void vtrans(
    const unsigned short* __restrict__ qkv, unsigned short* __restrict__ vt) {
  __shared__ unsigned short t[64][65];
  int b = blockIdx.y >> 4, h = blockIdx.y & 15;
  int n0 = blockIdx.x * 64;
  int tx = threadIdx.x & 63, ty = threadIdx.x >> 6;
  const unsigned short* src = qkv + ((size_t)(b * N_TOK + n0)) * (3 * DIM_) + 2 * DIM_ + h * DH_;
  #pragma unroll
  for (int r = ty; r < 64; r += 4) t[r][tx] = src[(size_t)r * (3 * DIM_) + tx];
  __syncthreads();
  unsigned short* dst = vt + ((size_t)blockIdx.y * DH_) * N_TOK + n0;
  #pragma unroll
  for (int r = ty; r < 64; r += 4) dst[(size_t)r * N_TOK + tx] = t[tx][r];
}

// ---------------------------------------------------------------------------
// 256x256 / BK=64 / 8-wave (2x4) bf16 MFMA GEMM, 2-phase (T3-minimum),
// T2 XOR-swizzled LDS (k_byte ^= (row&7)<<4), staged via inverse-swizzled
// global source + linear global_load_lds dest (rule #21).
// Per wave: 128x64 output = 8x4 16x16 frags; 64 MFMA per K-step barrier.
// grid (M/256, Nn/256, nsplit); split-K writes bf16 partials to Cb[z].
// EP 0: bf16 = acc+bias ; EP 1: bf16 = gelu(acc+bias) ;
// EP 3: bf16 raw partial (bias/residual applied in fused LN).
// ---------------------------------------------------------------------------
#define EP_BF16       0
#define EP_BF16_GELU  1
#define EP_BF16_PART  3

template <int EP>
__global__ __launch_bounds__(512, 2) void gemm256(
    const unsigned short* __restrict__ A, const unsigned short* __restrict__ Bt,
    const float* __restrict__ bias, unsigned short* __restrict__ Cb,
    int M, int Nn, int K) {
  int brow = blockIdx.x * 256;
  int bcol = blockIdx.y * 256;
  int Ks = K / gridDim.z;
  int kbase = blockIdx.z * Ks;
  int tid = threadIdx.x, lane = tid & 63, wave = tid >> 6;   // 8 waves
  int i = lane & 15, g = lane >> 4;
  int wr = wave >> 2, wc = wave & 3;                          // 2 x 4
  __shared__ unsigned short Al[2][256 * 64];                  // 64 KB
  __shared__ unsigned short Bl[2][256 * 64];                  // 64 KB

  f32x4 zero4 = {0.f, 0.f, 0.f, 0.f};
  f32x4 acc[8][4];
  #pragma unroll
  for (int m = 0; m < 8; ++m)
    #pragma unroll
    for (int n = 0; n < 4; ++n) acc[m][n] = zero4;

  // Stage one 256x64 tile for A and B: 32 chunks of 1KB (8 rows x 64 k);
  // wave w stages chunks w*4..w*4+3. LDS dest linear; source k pre-swizzled
  // so that LDS[row][ks] = A[row][ks ^ ((row&7)<<3)]  (ks = k in shorts).
  auto stage = [&](int buf, int k0) {
    #pragma unroll
    for (int j = 0; j < 4; ++j) {
      int c = wave * 4 + j;                       // wave-uniform chunk id
      int row = c * 8 + (lane >> 3);
      int kel = ((lane & 7) ^ (lane >> 3)) << 3;  // inverse-swizzled k element
      gload_lds16(A + (size_t)(brow + row) * K + kbase + k0 + kel, &Al[buf][c * 512]);
      gload_lds16(Bt + (size_t)(bcol + row) * K + kbase + k0 + kel, &Bl[buf][c * 512]);
    }
  };

  int NT = Ks / 64;
  stage(0, 0);
  for (int t = 0; t < NT; ++t) {
    __syncthreads();                              // tile t staged block-wide
    if (t + 1 < NT) stage((t + 1) & 1, (t + 1) * 64);
    int buf = t & 1;
    #pragma unroll
    for (int kk = 0; kk < 2; ++kk) {
      bf16x8 af[8], bfr[4];
      #pragma unroll
      for (int m = 0; m < 8; ++m) {
        int row = wr * 128 + m * 16 + i;
        af[m] = *reinterpret_cast<const bf16x8*>(
            &Al[buf][row * 64 + ((kk * 32 + g * 8) ^ ((i & 7) << 3))]);
      }
      #pragma unroll
      for (int n = 0; n < 4; ++n) {
        int row = wc * 64 + n * 16 + i;
        bfr[n] = *reinterpret_cast<const bf16x8*>(
            &Bl[buf][row * 64 + ((kk * 32 + g * 8) ^ ((i & 7) << 3))]);
      }
      #pragma unroll
      for (int m = 0; m < 8; ++m)
        #pragma unroll
        for (int n = 0; n < 4; ++n)
          acc[m][n] = mfma16(af[m], bfr[n], acc[m][n]);
    }
  }

  int rowbase = brow + wr * 128;
  int colbase = bcol + wc * 64;
  #pragma unroll
  for (int m = 0; m < 8; ++m) {
    #pragma unroll
    for (int n = 0; n < 4; ++n) {
      int col = colbase + n * 16 + i;
      #pragma unroll
      for (int r = 0; r < 4; ++r) {
        int row = rowbase + m * 16 + g * 4 + r;
        if constexpr (EP == EP_BF16) {
          float v = acc[m][n][r] + bias[col];
          Cb[(size_t)row * Nn + col] = f2bf(v);
        } else if constexpr (EP == EP_BF16_GELU) {
          float v = acc[m][n][r] + bias[col];
          float gg = 0.5f * v * (1.0f + erff(v * 0.70710678118f));
          Cb[(size_t)row * Nn + col] = f2bf(gg);
        } else {
          Cb[(size_t)blockIdx.z * PSTR_ + (size_t)row * Nn + col] = f2bf(acc[m][n][r]);
        }
      }
    }
  }
}

// ---------------------------------------------------------------------------
// Flash attention fwd, swapped-QK^T 32x32 MFMA, in-register softmax.
// grid (N_TOK/128, B_*HEADS_), 256 threads = 4 waves x 32 q-rows. (R2-validated)
// ---------------------------------------------------------------------------
__global__ __launch_bounds__(256) void attn_kernel(
    const unsigned short* __restrict__ qkv, const unsigned short* __restrict__ vt,
    unsigned short* __restrict__ o) {
  int qt = blockIdx.x, bh = blockIdx.y;
  int b = bh >> 4, h = bh & 15;
  int tid = threadIdx.x, lane = tid & 63, wave = tid >> 6;
  int q5 = lane & 31, hi = lane >> 5;
  __shared__ unsigned short Kl[2][64 * 64];
  __shared__ unsigned short Vl[2][64 * 64];

  const size_t qstr = 3 * DIM_;
  int qrow = qt * 128 + wave * 32 + q5;

  bf16x8 qa[4];
  #pragma unroll
  for (int f = 0; f < 4; ++f)
    qa[f] = *reinterpret_cast<const bf16x8*>(
        qkv + (size_t)(b * N_TOK + qrow) * qstr + h * DH_ + f * 16 + hi * 8);

  f32x16 oacc[2];
  oacc[0] = zero16(); oacc[1] = zero16();
  float m = -1e30f, l = 0.f;

  const unsigned short* kbase = qkv + (size_t)b * N_TOK * qstr + DIM_ + h * DH_;
  const unsigned short* vbase = vt + (size_t)bh * DH_ * N_TOK;
  uint4 kreg[2], vreg[2];

  auto issue = [&](int j0) {
    #pragma unroll
    for (int p = 0; p < 2; ++p) {
      int c = p * 256 + tid;
      int row = c >> 3, off = c & 7;
      kreg[p] = *reinterpret_cast<const uint4*>(kbase + (size_t)(j0 + row) * qstr + off * 8);
      vreg[p] = *reinterpret_cast<const uint4*>(vbase + (size_t)row * N_TOK + j0 + off * 8);
    }
  };
  auto commit = [&](int buf) {
    #pragma unroll
    for (int p = 0; p < 2; ++p) {
      int c = p * 256 + tid;
      int row = c >> 3, off = c & 7;
      int sw = row * 64 + ((off * 8) ^ ((row & 7) << 3));
      *reinterpret_cast<uint4*>(&Kl[buf][sw]) = kreg[p];
      *reinterpret_cast<uint4*>(&Vl[buf][sw]) = vreg[p];
    }
  };

  issue(0); commit(0);
  int cur = 0;
  for (int jt = 0; jt < N_TOK / 64; ++jt) {
    __syncthreads();
    if (jt + 1 < N_TOK / 64) issue((jt + 1) * 64);

    f32x16 sacc0 = zero16(), sacc1 = zero16();
    #pragma unroll
    for (int f = 0; f < 4; ++f) {
      int r0 = q5;
      int r1 = 32 + q5;
      bf16x8 ka0 = *reinterpret_cast<const bf16x8*>(
          &Kl[cur][r0 * 64 + ((f * 16 + hi * 8) ^ ((r0 & 7) << 3))]);
      bf16x8 ka1 = *reinterpret_cast<const bf16x8*>(
          &Kl[cur][r1 * 64 + ((f * 16 + hi * 8) ^ ((r1 & 7) << 3))]);
      sacc0 = mfma32(ka0, qa[f], sacc0);
      sacc1 = mfma32(ka1, qa[f], sacc1);
    }

    float pe0[16], pe1[16];
    float tmax = -1e30f;
    #pragma unroll
    for (int r = 0; r < 16; ++r) {
      pe0[r] = sacc0[r] * SCALE_;
      pe1[r] = sacc1[r] * SCALE_;
      tmax = fmaxf(tmax, fmaxf(pe0[r], pe1[r]));
    }
    tmax = fmaxf(tmax, __shfl_xor(tmax, 32));
    float mn = fmaxf(m, tmax);
    float al = __expf(m - mn);
    m = mn;
    float ps = 0.f;
    #pragma unroll
    for (int r = 0; r < 16; ++r) {
      pe0[r] = __expf(pe0[r] - mn); ps += pe0[r];
      pe1[r] = __expf(pe1[r] - mn); ps += pe1[r];
    }
    ps += __shfl_xor(ps, 32);
    l = l * al + ps;
    oacc[0] *= al;
    oacc[1] *= al;

    unsigned int cc0[8], cc1[8], dd0[8], dd1[8];
    #pragma unroll
    for (int t = 0; t < 8; ++t) {
      union { __bf16 hh[2]; unsigned int u; } p0, p1;
      p0.hh[0] = (__bf16)pe0[2 * t]; p0.hh[1] = (__bf16)pe0[2 * t + 1];
      p1.hh[0] = (__bf16)pe1[2 * t]; p1.hh[1] = (__bf16)pe1[2 * t + 1];
      cc0[t] = p0.u; cc1[t] = p1.u;
      dd0[t] = __shfl_xor(p0.u, 32);
      dd1[t] = __shfl_xor(p1.u, 32);
    }
    bf16x8 pb[4];
    #pragma unroll
    for (int half = 0; half < 2; ++half) {
      int t0 = half * 4;
      union { unsigned int w[4]; bf16x8 v; } u0, u1;
      u0.w[0] = hi ? dd0[t0 + 2] : cc0[t0 + 0];
      u0.w[1] = hi ? dd0[t0 + 3] : cc0[t0 + 1];
      u0.w[2] = hi ? cc0[t0 + 2] : dd0[t0 + 0];
      u0.w[3] = hi ? cc0[t0 + 3] : dd0[t0 + 1];
      u1.w[0] = hi ? dd1[t0 + 2] : cc1[t0 + 0];
      u1.w[1] = hi ? dd1[t0 + 3] : cc1[t0 + 1];
      u1.w[2] = hi ? cc1[t0 + 2] : dd1[t0 + 0];
      u1.w[3] = hi ? cc1[t0 + 3] : dd1[t0 + 1];
      pb[half] = u0.v;
      pb[2 + half] = u1.v;
    }

    #pragma unroll
    for (int dt = 0; dt < 2; ++dt) {
      int row = dt * 32 + q5;
      #pragma unroll
      for (int ks = 0; ks < 4; ++ks) {
        bf16x8 va = *reinterpret_cast<const bf16x8*>(
            &Vl[cur][row * 64 + ((ks * 16 + hi * 8) ^ ((row & 7) << 3))]);
        oacc[dt] = mfma32(va, pb[ks], oacc[dt]);
      }
    }
    if (jt + 1 < N_TOK / 64) commit(cur ^ 1);
    cur ^= 1;
  }

  float inv = 1.0f / l;
  unsigned short* ob = o + (size_t)(b * N_TOK + qrow) * DIM_ + h * DH_;
  #pragma unroll
  for (int dt = 0; dt < 2; ++dt)
    #pragma unroll
    for (int rq = 0; rq < 4; ++rq) {
      ushort4 st;
      st.x = f2bf(oacc[dt][rq * 4 + 0] * inv);
      st.y = f2bf(oacc[dt][rq * 4 + 1] * inv);
      st.z = f2bf(oacc[dt][rq * 4 + 2] * inv);
      st.w = f2bf(oacc[dt][rq * 4 + 3] * inv);
      *reinterpret_cast<ushort4*>(ob + dt * 32 + rq * 8 + hi * 4) = st;
    }
}

// ---------------------------------------------------------------------------
extern "C" void kernel_launch(void* const* d_in, const int* in_sizes, int n_in,
                              void* d_out, int out_size, void* d_ws, size_t ws_size,
                              hipStream_t stream) {
  (void)in_sizes; (void)n_in; (void)out_size; (void)ws_size;
  const float* x_in = (const float*)d_in[0];
  const float* Wqkv = (const float*)d_in[1];
  const float* bqkv = (const float*)d_in[2];
  const float* Wo   = (const float*)d_in[3];
  const float* bo   = (const float*)d_in[4];
  const float* W1   = (const float*)d_in[5];
  const float* bm1  = (const float*)d_in[6];
  const float* W2   = (const float*)d_in[7];
  const float* bm2  = (const float*)d_in[8];
  const float* ln1g = (const float*)d_in[9];
  const float* ln1b = (const float*)d_in[10];
  const float* ln2g = (const float*)d_in[11];
  const float* ln2b = (const float*)d_in[12];
  float* x = (float*)d_out;                  // residual stream, fp32, in-place

  // ws layout — 88 MB total (same footprint proven through R4).
  // parts (bf16, 4 x 8 MB) ALIASES qkv+vtb: those are dead after attn_kernel,
  // and parts is consumed (by ln_fused/final_add) before qkv is rewritten.
  char* ws = (char*)d_ws;
  const size_t MB = 1024 * 1024;
  unsigned short* wt   = (unsigned short*)(ws);               // 0-8 MB (reused per GEMM)
  unsigned short* hbf  = (unsigned short*)(ws + 8  * MB);     // 8-16
  unsigned short* qkv  = (unsigned short*)(ws + 16 * MB);     // 16-40
  unsigned short* vtb  = (unsigned short*)(ws + 40 * MB);     // 40-48
  unsigned short* ob   = (unsigned short*)(ws + 48 * MB);     // 48-56
  unsigned short* mid  = (unsigned short*)(ws + 56 * MB);     // 56-88
  unsigned short* parts= (unsigned short*)(ws + 16 * MB);     // alias 16-48

  copy_x<<<4096, 256, 0, stream>>>((const float4*)x_in, (float4*)x);

  for (int l = 0; l < DEPTH_; ++l) {
    const float* wqkv_l = Wqkv + (size_t)l * DIM_ * 3 * DIM_;
    const float* wo_l   = Wo   + (size_t)l * DIM_ * DIM_;
    const float* w1_l   = W1   + (size_t)l * DIM_ * HID_;
    const float* w2_l   = W2   + (size_t)l * HID_ * DIM_;

    // LN1 (fused with previous layer's MLP2 split-K reduction + bm2 + residual)
    ln_fused<<<MROWS_, 256, 0, stream>>>(
        x, hbf, ln1g + l * DIM_, ln1b + l * DIM_,
        parts, l == 0 ? 0 : 4, l == 0 ? nullptr : bm2 + (size_t)(l - 1) * DIM_);

    // QKV: [4096,1024] x [1024,3072]
    transpose_w<<<dim3(3 * DIM_ / 32, DIM_ / 32), 256, 0, stream>>>(wqkv_l, wt, DIM_, 3 * DIM_);
    gemm256<EP_BF16><<<dim3(16, 12, 1), 512, 0, stream>>>(
        hbf, wt, bqkv + (size_t)l * 3 * DIM_, qkv, MROWS_, 3 * DIM_, DIM_);

    vtrans<<<dim3(N_TOK / 64, B_ * HEADS_), 256, 0, stream>>>(qkv, vtb);
    attn_kernel<<<dim3(N_TOK / 128, B_ * HEADS_), 256, 0, stream>>>(qkv, vtb, ob);

    // O-proj: split-K=4 -> bf16 partials (bias+residual applied in ln_fused)
    transpose_w<<<dim3(DIM_ / 32, DIM_ / 32), 256, 0, stream>>>(wo_l, wt, DIM_, DIM_);
    gemm256<EP_BF16_PART><<<dim3(16, 4, 4), 512, 0, stream>>>(
        ob, wt, nullptr, parts, MROWS_, DIM_, DIM_);

    // LN2 (fused with O-proj reduction + bo + residual)
    ln_fused<<<MROWS_, 256, 0, stream>>>(
        x, hbf, ln2g + l * DIM_, ln2b + l * DIM_, parts, 4, bo + (size_t)l * DIM_);

    // MLP1 with GELU epilogue
    transpose_w<<<dim3(HID_ / 32, DIM_ / 32), 256, 0, stream>>>(w1_l, wt, DIM_, HID_);
    gemm256<EP_BF16_GELU><<<dim3(16, 16, 1), 512, 0, stream>>>(
        hbf, wt, bm1 + (size_t)l * HID_, mid, MROWS_, HID_, DIM_);

    // MLP2: split-K=4 over K=4096 -> bf16 partials
    transpose_w<<<dim3(DIM_ / 32, HID_ / 32), 256, 0, stream>>>(w2_l, wt, HID_, DIM_);
    gemm256<EP_BF16_PART><<<dim3(16, 4, 4), 512, 0, stream>>>(
        mid, wt, nullptr, parts, MROWS_, DIM_, HID_);
  }

  // final residual update (last layer's MLP2 reduction + bm2[5])
  final_add<<<4096, 256, 0, stream>>>(x, parts, bm2 + (size_t)(DEPTH_ - 1) * DIM_);
}